// Round 9
// baseline (548.172 us; speedup 1.0000x reference)
//
#include <hip/hip_runtime.h>
#include <hip/hip_bf16.h>

#define B_TOT 131072
#define D     32
#define H1    50
#define QF    528      // tril feature count (k-row 528 = folded bias, 529..543 = 0)
#define H2    700
#define MROWS 32       // batch rows per block
#define QSTR  548      // quadls row stride (ushorts)

typedef __attribute__((ext_vector_type(8))) short  short8x;
typedef __attribute__((ext_vector_type(4))) float  floatx4;

static __device__ __forceinline__ unsigned short f2bf(float f) {
    __hip_bfloat16 h = __float2bfloat16(f);   // RNE
    return __builtin_bit_cast(unsigned short, h);
}
static __device__ __forceinline__ float bf2f(unsigned short u) {
    unsigned int x = (unsigned int)u << 16;
    return __builtin_bit_cast(float, x);
}
// clampless tanh: exp2 overflows to +inf -> rcp(inf)=0 -> 1; underflows to 0 -> -1.
static __device__ __forceinline__ float tanh_fast(float x) {
    float e = __builtin_amdgcn_exp2f(x * 2.885390082f);   // e^(2x)
    return 1.f - 2.f * __builtin_amdgcn_rcpf(e + 1.f);
}

// ---------------- prep: pre-fragmented bf16 weight layouts ----------------
// W2aT: [k=0..16][panel p=0..47][lane 0..63][j 0..7]  (417792 ushorts)
//   element = W2a[kk][c], kk = k*32+(lane>>4)*8+j, c = p*16+(lane&15)
//   kk==528 -> b2a[c]  (bias folded as extra K-row; quad k=528 is 1.0)
// W2bT: [wave w=0..15][ks=0..1][of=0..1][lane][j]     (32768 ushorts)
__global__ void prep_kernel(const float* __restrict__ W2a, const float* __restrict__ b2a,
                            const float* __restrict__ W2b,
                            unsigned short* __restrict__ W2aT,
                            unsigned short* __restrict__ W2bT) {
    int idx = blockIdx.x * 256 + threadIdx.x;
    const int N1 = 17 * 48 * 512;    // 417792
    const int N2 = 16 * 4 * 512;     // 32768
    if (idx < N1) {
        int k   = idx / (48 * 512);
        int rem = idx - k * (48 * 512);
        int p   = rem >> 9;
        int q   = rem & 511;
        int ln  = q >> 3, j = q & 7;
        int kk  = k * 32 + ((ln >> 4) << 3) + j;
        int c   = (p << 4) + (ln & 15);
        float v = 0.f;
        if (c < H2) {
            if (kk < QF)       v = W2a[kk * H2 + c];
            else if (kk == QF) v = b2a[c];
        }
        W2aT[idx] = f2bf(v);
    } else if (idx < N1 + N2) {
        int i2 = idx - N1;
        int q  = i2 & 511;
        int ln = q >> 3, j = q & 7;
        int w  = i2 >> 11;
        int ks = (i2 >> 10) & 1;
        int of = (i2 >> 9) & 1;
        int kl = (ks << 5) + ((ln >> 4) << 3) + j;   // local k 0..63
        int kg = w * 48 + kl;
        int c  = (of << 4) + (ln & 15);
        float v = (kl < 48 && kg < H2) ? W2b[kg * D + c] : 0.f;
        W2bT[i2] = f2bf(v);
    }
}

// ---------------- fused main kernel ----------------
// r8 geometry (32 rows, 16 waves, 2 blocks/CU, <=64 VGPR) + r9 VALU cuts:
// clampless tanh, 4-way chain-split reductions, packed u32 stage writes.
__global__ __launch_bounds__(1024, 8)
__attribute__((amdgpu_waves_per_eu(8, 8)))
void fused_kernel(
    const float* __restrict__ y,   const float* __restrict__ W1a,
    const float* __restrict__ b1a, const float* __restrict__ W1b,
    const float* __restrict__ b1b, const float* __restrict__ b2b,
    const unsigned short* __restrict__ W2aT, const unsigned short* __restrict__ W2bT,
    float* __restrict__ out) {

    __shared__ unsigned short quadls[MROWS][QSTR]; // 35072 B; post-K reused as bf16 stage [16][1024]
    __shared__ float          yls[MROWS][36];      //  4608 B
    __shared__ unsigned short hst[16][16][68];     // 34816 B  => total 74496 B (2 blocks/CU)

    const int tid  = threadIdx.x;
    const int lane = tid & 63;
    const int w    = tid >> 6;                         // wave 0..15
    const int wu   = __builtin_amdgcn_readfirstlane(w);
    const int l15  = lane & 15;
    const int lg   = lane >> 4;                        // 0..3
    const int row0 = blockIdx.x * MROWS;

    // ---- Phase A: y tile (coalesced); zero hst K-pad cols 48..63 (wave-local) ----
    yls[tid >> 5][tid & 31] = y[row0 * D + tid];
    {
        int rr = lane >> 2, cc0 = 48 + (lane & 3) * 4;
        *reinterpret_cast<unsigned long long*>(&hst[w][rr][cc0]) = 0ULL;
    }
    __syncthreads();

    // ---- Phase B: quad build (1 (row,i) task/thread) + bias-one + K-pad ----
    {
        int r = tid >> 5, i = tid & 31;
        int base = (i * (i + 1)) >> 1;
        float yi = yls[r][i];
        for (int j4 = 0; j4 <= i; j4 += 4) {
            floatx4 yv = *reinterpret_cast<const floatx4*>(&yls[r][j4]);
            #pragma unroll
            for (int jj = 0; jj < 4; ++jj) {
                int j = j4 + jj;
                if (j <= i) quadls[r][base + j] = f2bf(yi * yv[jj]);
            }
        }
    }
    if (tid < 512) {   // cols 528..543: 528 = 1.0 (bias row), rest 0
        int r = tid >> 4, c = 528 + (tid & 15);
        quadls[r][c] = (c == 528) ? (unsigned short)0x3F80 : (unsigned short)0;
    }
    __syncthreads();

    // ---- K-loop: wave w owns hidden cols [w*48, w*48+48) ----
    floatx4 hacc00 = {0,0,0,0}, hacc01 = {0,0,0,0}, hacc02 = {0,0,0,0};
    floatx4 hacc10 = {0,0,0,0}, hacc11 = {0,0,0,0}, hacc12 = {0,0,0,0};
    {
        const unsigned short* bp = W2aT + wu * 3 * 512 + lane * 8;
        #pragma unroll 1
        for (int k = 0; k < 17; ++k) {
            short8x a0 = *reinterpret_cast<const short8x*>(&quadls[l15][k * 32 + lg * 8]);
            short8x a1 = *reinterpret_cast<const short8x*>(&quadls[16 + l15][k * 32 + lg * 8]);
            short8x b0 = *reinterpret_cast<const short8x*>(bp);
            short8x b1 = *reinterpret_cast<const short8x*>(bp + 512);
            short8x b2 = *reinterpret_cast<const short8x*>(bp + 1024);
            hacc00 = __builtin_amdgcn_mfma_f32_16x16x32_bf16(a0, b0, hacc00, 0, 0, 0);
            hacc01 = __builtin_amdgcn_mfma_f32_16x16x32_bf16(a0, b1, hacc01, 0, 0, 0);
            hacc02 = __builtin_amdgcn_mfma_f32_16x16x32_bf16(a0, b2, hacc02, 0, 0, 0);
            hacc10 = __builtin_amdgcn_mfma_f32_16x16x32_bf16(a1, b0, hacc10, 0, 0, 0);
            hacc11 = __builtin_amdgcn_mfma_f32_16x16x32_bf16(a1, b1, hacc11, 0, 0, 0);
            hacc12 = __builtin_amdgcn_mfma_f32_16x16x32_bf16(a1, b2, hacc12, 0, 0, 0);
            bp += 48 * 512;
        }
    }

    // ---- net1 in registers (pre-barrier; no shared-state hazard) ----
    // wave w -> rows {w*2, w*2+1}, half-wave per row; 4-way chain splits.
    float o1;
    {
        int rowa = (tid >> 5);            // == w*2 + (lane>>5)
        int c    = lane & 31;
        const float* yr = &yls[rowa][0];
        float h1a, h1b = 0.f;
        {
            float p0 = 0.f, p1 = 0.f, p2 = 0.f, p3 = 0.f;
            #pragma unroll
            for (int i = 0; i < 32; i += 4) {
                p0 += yr[i]     * W1a[i * H1 + c];
                p1 += yr[i + 1] * W1a[(i + 1) * H1 + c];
                p2 += yr[i + 2] * W1a[(i + 2) * H1 + c];
                p3 += yr[i + 3] * W1a[(i + 3) * H1 + c];
            }
            h1a = tanh_fast(b1a[c] + ((p0 + p1) + (p2 + p3)));
        }
        if (c < H1 - 32) {
            float p0 = 0.f, p1 = 0.f, p2 = 0.f, p3 = 0.f;
            #pragma unroll
            for (int i = 0; i < 32; i += 4) {
                p0 += yr[i]     * W1a[i * H1 + 32 + c];
                p1 += yr[i + 1] * W1a[(i + 1) * H1 + 32 + c];
                p2 += yr[i + 2] * W1a[(i + 2) * H1 + 32 + c];
                p3 += yr[i + 3] * W1a[(i + 3) * H1 + 32 + c];
            }
            h1b = tanh_fast(b1a[32 + c] + ((p0 + p1) + (p2 + p3)));
        }
        float q0 = 0.f, q1 = 0.f, q2 = 0.f, q3 = 0.f;
        #pragma unroll
        for (int k = 0; k < 32; k += 4) {
            q0 += __shfl(h1a, (lane & 32) + k)     * W1b[k * D + c];
            q1 += __shfl(h1a, (lane & 32) + k + 1) * W1b[(k + 1) * D + c];
            q2 += __shfl(h1a, (lane & 32) + k + 2) * W1b[(k + 2) * D + c];
            q3 += __shfl(h1a, (lane & 32) + k + 3) * W1b[(k + 3) * D + c];
        }
        #pragma unroll
        for (int k = 0; k < 18; k += 2) {
            q0 += __shfl(h1b, (lane & 32) + k)     * W1b[(32 + k) * D + c];
            q1 += __shfl(h1b, (lane & 32) + k + 1) * W1b[(33 + k) * D + c];
        }
        o1 = (b1b[c] + b2b[c]) + ((q0 + q1) + (q2 + q3));
    }
    __syncthreads();   // all quadls K-reads complete -> stage region is free

    // ---- epilogue: tanh -> hst -> GEMM2 (transient o2) -> packed bf16 stage ----
    // stage layout: flat f = row*32 + 2*l15 + of  holds col (of*16 + l15)
    unsigned short* stage = &quadls[0][0];
    {
        const unsigned short* wb = W2bT + wu * 4 * 512 + lane * 8;
        #pragma unroll
        for (int m = 0; m < 2; ++m) {
            const floatx4 h0 = m ? hacc10 : hacc00;
            const floatx4 h1 = m ? hacc11 : hacc01;
            const floatx4 h2 = m ? hacc12 : hacc02;
            #pragma unroll
            for (int r = 0; r < 4; ++r) {
                hst[w][lg * 4 + r][l15]      = f2bf(tanh_fast(h0[r]));
                hst[w][lg * 4 + r][16 + l15] = f2bf(tanh_fast(h1[r]));
                hst[w][lg * 4 + r][32 + l15] = f2bf(tanh_fast(h2[r]));
            }
            short8x aa0 = *reinterpret_cast<const short8x*>(&hst[w][l15][lg * 8]);
            short8x aa1 = *reinterpret_cast<const short8x*>(&hst[w][l15][32 + lg * 8]);
            floatx4 o20 = {0,0,0,0}, o21 = {0,0,0,0};
            {
                short8x bw00 = *reinterpret_cast<const short8x*>(wb);
                short8x bw01 = *reinterpret_cast<const short8x*>(wb + 512);
                o20 = __builtin_amdgcn_mfma_f32_16x16x32_bf16(aa0, bw00, o20, 0, 0, 0);
                o21 = __builtin_amdgcn_mfma_f32_16x16x32_bf16(aa0, bw01, o21, 0, 0, 0);
            }
            {
                short8x bw10 = *reinterpret_cast<const short8x*>(wb + 1024);
                short8x bw11 = *reinterpret_cast<const short8x*>(wb + 1536);
                o20 = __builtin_amdgcn_mfma_f32_16x16x32_bf16(aa1, bw10, o20, 0, 0, 0);
                o21 = __builtin_amdgcn_mfma_f32_16x16x32_bf16(aa1, bw11, o21, 0, 0, 0);
            }
            #pragma unroll
            for (int r = 0; r < 4; ++r) {
                int row = m * 16 + lg * 4 + r;
                unsigned int pk = ((unsigned int)f2bf(o21[r]) << 16) | (unsigned int)f2bf(o20[r]);
                *reinterpret_cast<unsigned int*>(&stage[wu * 1024 + row * 32 + l15 * 2]) = pk;
            }
        }
    }
    __syncthreads();   // all stage writes visible

    // ---- reduce 16 bf16 panels + out1 (4-way chains), natural coalesced store ----
    {
        int c  = tid & 31;
        int fr = (tid & ~31) + ((c & 15) << 1) + (c >> 4);   // remapped flat offset
        float s0 = 0.f, s1 = 0.f, s2 = 0.f, s3 = 0.f;
        #pragma unroll
        for (int p = 0; p < 16; p += 4) {
            s0 += bf2f(stage[p * 1024 + fr]);
            s1 += bf2f(stage[(p + 1) * 1024 + fr]);
            s2 += bf2f(stage[(p + 2) * 1024 + fr]);
            s3 += bf2f(stage[(p + 3) * 1024 + fr]);
        }
        out[row0 * D + tid] = o1 + ((s0 + s1) + (s2 + s3));
    }
}

extern "C" void kernel_launch(void* const* d_in, const int* in_sizes, int n_in,
                              void* d_out, int out_size, void* d_ws, size_t ws_size,
                              hipStream_t stream) {
    const float* y   = (const float*)d_in[1];
    const float* W1a = (const float*)d_in[2];
    const float* b1a = (const float*)d_in[3];
    const float* W1b = (const float*)d_in[4];
    const float* b1b = (const float*)d_in[5];
    const float* W2a = (const float*)d_in[6];
    const float* b2a = (const float*)d_in[7];
    const float* W2b = (const float*)d_in[8];
    const float* b2b = (const float*)d_in[9];

    unsigned short* W2aT = (unsigned short*)d_ws;                      // 835584 B
    unsigned short* W2bT = (unsigned short*)((char*)d_ws + 835584);    //  65536 B

    const int prep_tasks = 17 * 48 * 512 + 16 * 4 * 512;               // 450560
    prep_kernel<<<(prep_tasks + 255) / 256, 256, 0, stream>>>(W2a, b2a, W2b, W2aT, W2bT);
    fused_kernel<<<B_TOT / MROWS, 1024, 0, stream>>>(y, W1a, b1a, W1b, b1b, b2b,
                                                     W2aT, W2bT, (float*)d_out);
}

// Round 10
// 340.659 us; speedup vs baseline: 1.6092x; 1.6092x over previous
//
#include <hip/hip_runtime.h>
#include <hip/hip_bf16.h>

#define B_TOT 131072
#define D     32
#define H1    50
#define QF    528      // tril feature count (k-row 528 = folded bias, 529..543 = 0)
#define H2    700
#define MROWS 32       // batch rows per block
#define QSTR  548      // quadls row stride (ushorts)

typedef __attribute__((ext_vector_type(8))) short  short8x;
typedef __attribute__((ext_vector_type(4))) float  floatx4;

static __device__ __forceinline__ unsigned short f2bf(float f) {
    __hip_bfloat16 h = __float2bfloat16(f);   // RNE
    return __builtin_bit_cast(unsigned short, h);
}
static __device__ __forceinline__ float bf2f(unsigned short u) {
    unsigned int x = (unsigned int)u << 16;
    return __builtin_bit_cast(float, x);
}
// clampless tanh: exp2 overflows to +inf -> rcp(inf)=0 -> 1; underflows to 0 -> -1.
static __device__ __forceinline__ float tanh_fast(float x) {
    float e = __builtin_amdgcn_exp2f(x * 2.885390082f);   // e^(2x)
    return 1.f - 2.f * __builtin_amdgcn_rcpf(e + 1.f);
}

// ---------------- prep: pre-fragmented bf16 weight layouts ----------------
// W2aT: [k=0..16][panel p=0..47][lane 0..63][j 0..7]  (417792 ushorts)
//   element = W2a[kk][c], kk = k*32+(lane>>4)*8+j, c = p*16+(lane&15)
//   kk==528 -> b2a[c]  (bias folded as extra K-row; quad k=528 is 1.0)
// W2bT: [wave w=0..15][ks=0..1][of=0..1][lane][j]     (32768 ushorts)
__global__ void prep_kernel(const float* __restrict__ W2a, const float* __restrict__ b2a,
                            const float* __restrict__ W2b,
                            unsigned short* __restrict__ W2aT,
                            unsigned short* __restrict__ W2bT) {
    int idx = blockIdx.x * 256 + threadIdx.x;
    const int N1 = 17 * 48 * 512;    // 417792
    const int N2 = 16 * 4 * 512;     // 32768
    if (idx < N1) {
        int k   = idx / (48 * 512);
        int rem = idx - k * (48 * 512);
        int p   = rem >> 9;
        int q   = rem & 511;
        int ln  = q >> 3, j = q & 7;
        int kk  = k * 32 + ((ln >> 4) << 3) + j;
        int c   = (p << 4) + (ln & 15);
        float v = 0.f;
        if (c < H2) {
            if (kk < QF)       v = W2a[kk * H2 + c];
            else if (kk == QF) v = b2a[c];
        }
        W2aT[idx] = f2bf(v);
    } else if (idx < N1 + N2) {
        int i2 = idx - N1;
        int q  = i2 & 511;
        int ln = q >> 3, j = q & 7;
        int w  = i2 >> 11;
        int ks = (i2 >> 10) & 1;
        int of = (i2 >> 9) & 1;
        int kl = (ks << 5) + ((ln >> 4) << 3) + j;   // local k 0..63
        int kg = w * 48 + kl;
        int c  = (of << 4) + (ln & 15);
        float v = (kl < 48 && kg < H2) ? W2b[kg * D + c] : 0.f;
        W2bT[i2] = f2bf(v);
    }
}

// ---------------- fused main kernel ----------------
// r8 geometry AND r8 phase order (K-loop -> barrier -> epilogue -> net1 ->
// barrier -> reduce). PHASE ORDER IS LOAD-BEARING: net1 must run after the
// epilogue so its ~25 live regs don't overlap the 24 hacc accumulators
// (r9 moved it pre-barrier -> live sets overlapped -> 64-reg budget blown
// -> 2.2 GB of spill traffic, 548 us). Keeps r9's VALU cuts: clampless
// exp2-tanh, 4-way chain-split reductions, packed u32 stage writes.
__global__ __launch_bounds__(1024, 8)
__attribute__((amdgpu_waves_per_eu(8, 8)))
void fused_kernel(
    const float* __restrict__ y,   const float* __restrict__ W1a,
    const float* __restrict__ b1a, const float* __restrict__ W1b,
    const float* __restrict__ b1b, const float* __restrict__ b2b,
    const unsigned short* __restrict__ W2aT, const unsigned short* __restrict__ W2bT,
    float* __restrict__ out) {

    __shared__ unsigned short quadls[MROWS][QSTR]; // 35072 B; post-K reused as bf16 stage [16][1024]
    __shared__ float          yls[MROWS][36];      //  4608 B
    __shared__ unsigned short hst[16][16][68];     // 34816 B  => total 74496 B (2 blocks/CU)

    const int tid  = threadIdx.x;
    const int lane = tid & 63;
    const int w    = tid >> 6;                         // wave 0..15
    const int wu   = __builtin_amdgcn_readfirstlane(w);
    const int l15  = lane & 15;
    const int lg   = lane >> 4;                        // 0..3
    const int row0 = blockIdx.x * MROWS;

    // ---- Phase A: y tile (coalesced); zero hst K-pad cols 48..63 (wave-local) ----
    yls[tid >> 5][tid & 31] = y[row0 * D + tid];
    {
        int rr = lane >> 2, cc0 = 48 + (lane & 3) * 4;
        *reinterpret_cast<unsigned long long*>(&hst[w][rr][cc0]) = 0ULL;
    }
    __syncthreads();

    // ---- Phase B: quad build (1 (row,i) task/thread) + bias-one + K-pad ----
    {
        int r = tid >> 5, i = tid & 31;
        int base = (i * (i + 1)) >> 1;
        float yi = yls[r][i];
        for (int j4 = 0; j4 <= i; j4 += 4) {
            floatx4 yv = *reinterpret_cast<const floatx4*>(&yls[r][j4]);
            #pragma unroll
            for (int jj = 0; jj < 4; ++jj) {
                int j = j4 + jj;
                if (j <= i) quadls[r][base + j] = f2bf(yi * yv[jj]);
            }
        }
    }
    if (tid < 512) {   // cols 528..543: 528 = 1.0 (bias row), rest 0
        int r = tid >> 4, c = 528 + (tid & 15);
        quadls[r][c] = (c == 528) ? (unsigned short)0x3F80 : (unsigned short)0;
    }
    __syncthreads();

    // ---- K-loop: wave w owns hidden cols [w*48, w*48+48) ----
    floatx4 hacc00 = {0,0,0,0}, hacc01 = {0,0,0,0}, hacc02 = {0,0,0,0};
    floatx4 hacc10 = {0,0,0,0}, hacc11 = {0,0,0,0}, hacc12 = {0,0,0,0};
    {
        const unsigned short* bp = W2aT + wu * 3 * 512 + lane * 8;
        #pragma unroll 1
        for (int k = 0; k < 17; ++k) {
            short8x a0 = *reinterpret_cast<const short8x*>(&quadls[l15][k * 32 + lg * 8]);
            short8x a1 = *reinterpret_cast<const short8x*>(&quadls[16 + l15][k * 32 + lg * 8]);
            short8x b0 = *reinterpret_cast<const short8x*>(bp);
            short8x b1 = *reinterpret_cast<const short8x*>(bp + 512);
            short8x b2 = *reinterpret_cast<const short8x*>(bp + 1024);
            hacc00 = __builtin_amdgcn_mfma_f32_16x16x32_bf16(a0, b0, hacc00, 0, 0, 0);
            hacc01 = __builtin_amdgcn_mfma_f32_16x16x32_bf16(a0, b1, hacc01, 0, 0, 0);
            hacc02 = __builtin_amdgcn_mfma_f32_16x16x32_bf16(a0, b2, hacc02, 0, 0, 0);
            hacc10 = __builtin_amdgcn_mfma_f32_16x16x32_bf16(a1, b0, hacc10, 0, 0, 0);
            hacc11 = __builtin_amdgcn_mfma_f32_16x16x32_bf16(a1, b1, hacc11, 0, 0, 0);
            hacc12 = __builtin_amdgcn_mfma_f32_16x16x32_bf16(a1, b2, hacc12, 0, 0, 0);
            bp += 48 * 512;
        }
    }
    __syncthreads();   // all quadls K-reads complete -> stage region is free

    // ---- epilogue: tanh -> hst -> GEMM2 (transient o2) -> packed bf16 stage ----
    // stage layout: flat f = row*32 + 2*l15 + of  holds col (of*16 + l15)
    unsigned short* stage = &quadls[0][0];
    {
        const unsigned short* wb = W2bT + wu * 4 * 512 + lane * 8;
        #pragma unroll
        for (int m = 0; m < 2; ++m) {
            const floatx4 h0 = m ? hacc10 : hacc00;
            const floatx4 h1 = m ? hacc11 : hacc01;
            const floatx4 h2 = m ? hacc12 : hacc02;
            #pragma unroll
            for (int r = 0; r < 4; ++r) {
                hst[w][lg * 4 + r][l15]      = f2bf(tanh_fast(h0[r]));
                hst[w][lg * 4 + r][16 + l15] = f2bf(tanh_fast(h1[r]));
                hst[w][lg * 4 + r][32 + l15] = f2bf(tanh_fast(h2[r]));
            }
            short8x aa0 = *reinterpret_cast<const short8x*>(&hst[w][l15][lg * 8]);
            short8x aa1 = *reinterpret_cast<const short8x*>(&hst[w][l15][32 + lg * 8]);
            floatx4 o20 = {0,0,0,0}, o21 = {0,0,0,0};
            {
                short8x bw00 = *reinterpret_cast<const short8x*>(wb);
                short8x bw01 = *reinterpret_cast<const short8x*>(wb + 512);
                o20 = __builtin_amdgcn_mfma_f32_16x16x32_bf16(aa0, bw00, o20, 0, 0, 0);
                o21 = __builtin_amdgcn_mfma_f32_16x16x32_bf16(aa0, bw01, o21, 0, 0, 0);
            }
            {
                short8x bw10 = *reinterpret_cast<const short8x*>(wb + 1024);
                short8x bw11 = *reinterpret_cast<const short8x*>(wb + 1536);
                o20 = __builtin_amdgcn_mfma_f32_16x16x32_bf16(aa1, bw10, o20, 0, 0, 0);
                o21 = __builtin_amdgcn_mfma_f32_16x16x32_bf16(aa1, bw11, o21, 0, 0, 0);
            }
            #pragma unroll
            for (int r = 0; r < 4; ++r) {
                int row = m * 16 + lg * 4 + r;
                unsigned int pk = ((unsigned int)f2bf(o21[r]) << 16) | (unsigned int)f2bf(o20[r]);
                *reinterpret_cast<unsigned int*>(&stage[wu * 1024 + row * 32 + l15 * 2]) = pk;
            }
        }
    }

    // ---- net1 in registers (hacc dead now; live sets disjoint) ----
    // wave w -> rows {w*2, w*2+1}, half-wave per row; 4-way chain splits.
    float o1;
    {
        int rowa = (tid >> 5);            // == w*2 + (lane>>5)
        int c    = lane & 31;
        const float* yr = &yls[rowa][0];
        float h1a, h1b = 0.f;
        {
            float p0 = 0.f, p1 = 0.f, p2 = 0.f, p3 = 0.f;
            #pragma unroll
            for (int i = 0; i < 32; i += 4) {
                p0 += yr[i]     * W1a[i * H1 + c];
                p1 += yr[i + 1] * W1a[(i + 1) * H1 + c];
                p2 += yr[i + 2] * W1a[(i + 2) * H1 + c];
                p3 += yr[i + 3] * W1a[(i + 3) * H1 + c];
            }
            h1a = tanh_fast(b1a[c] + ((p0 + p1) + (p2 + p3)));
        }
        if (c < H1 - 32) {
            float p0 = 0.f, p1 = 0.f, p2 = 0.f, p3 = 0.f;
            #pragma unroll
            for (int i = 0; i < 32; i += 4) {
                p0 += yr[i]     * W1a[i * H1 + 32 + c];
                p1 += yr[i + 1] * W1a[(i + 1) * H1 + 32 + c];
                p2 += yr[i + 2] * W1a[(i + 2) * H1 + 32 + c];
                p3 += yr[i + 3] * W1a[(i + 3) * H1 + 32 + c];
            }
            h1b = tanh_fast(b1a[32 + c] + ((p0 + p1) + (p2 + p3)));
        }
        float q0 = 0.f, q1 = 0.f, q2 = 0.f, q3 = 0.f;
        #pragma unroll
        for (int k = 0; k < 32; k += 4) {
            q0 += __shfl(h1a, (lane & 32) + k)     * W1b[k * D + c];
            q1 += __shfl(h1a, (lane & 32) + k + 1) * W1b[(k + 1) * D + c];
            q2 += __shfl(h1a, (lane & 32) + k + 2) * W1b[(k + 2) * D + c];
            q3 += __shfl(h1a, (lane & 32) + k + 3) * W1b[(k + 3) * D + c];
        }
        #pragma unroll
        for (int k = 0; k < 18; k += 2) {
            q0 += __shfl(h1b, (lane & 32) + k)     * W1b[(32 + k) * D + c];
            q1 += __shfl(h1b, (lane & 32) + k + 1) * W1b[(33 + k) * D + c];
        }
        o1 = (b1b[c] + b2b[c]) + ((q0 + q1) + (q2 + q3));
    }
    __syncthreads();   // all stage writes visible

    // ---- reduce 16 bf16 panels + out1 (4-way chains), natural coalesced store ----
    {
        int c  = tid & 31;
        int fr = (tid & ~31) + ((c & 15) << 1) + (c >> 4);   // remapped flat offset
        float s0 = 0.f, s1 = 0.f, s2 = 0.f, s3 = 0.f;
        #pragma unroll
        for (int p = 0; p < 16; p += 4) {
            s0 += bf2f(stage[p * 1024 + fr]);
            s1 += bf2f(stage[(p + 1) * 1024 + fr]);
            s2 += bf2f(stage[(p + 2) * 1024 + fr]);
            s3 += bf2f(stage[(p + 3) * 1024 + fr]);
        }
        out[row0 * D + tid] = o1 + ((s0 + s1) + (s2 + s3));
    }
}

extern "C" void kernel_launch(void* const* d_in, const int* in_sizes, int n_in,
                              void* d_out, int out_size, void* d_ws, size_t ws_size,
                              hipStream_t stream) {
    const float* y   = (const float*)d_in[1];
    const float* W1a = (const float*)d_in[2];
    const float* b1a = (const float*)d_in[3];
    const float* W1b = (const float*)d_in[4];
    const float* b1b = (const float*)d_in[5];
    const float* W2a = (const float*)d_in[6];
    const float* b2a = (const float*)d_in[7];
    const float* W2b = (const float*)d_in[8];
    const float* b2b = (const float*)d_in[9];

    unsigned short* W2aT = (unsigned short*)d_ws;                      // 835584 B
    unsigned short* W2bT = (unsigned short*)((char*)d_ws + 835584);    //  65536 B

    const int prep_tasks = 17 * 48 * 512 + 16 * 4 * 512;               // 450560
    prep_kernel<<<(prep_tasks + 255) / 256, 256, 0, stream>>>(W2a, b2a, W2b, W2aT, W2bT);
    fused_kernel<<<B_TOT / MROWS, 1024, 0, stream>>>(y, W1a, b1a, W1b, b1b, b2b,
                                                     W2aT, W2bT, (float*)d_out);
}

// Round 11
// 164.441 us; speedup vs baseline: 3.3336x; 2.0716x over previous
//
#include <hip/hip_runtime.h>
#include <hip/hip_bf16.h>

#define B_TOT 131072
#define D     32
#define H1    50
#define QF    528      // tril feature count
#define H2    700
#define MROWS 32       // batch rows per block
#define QSTR  584      // quadls row stride (ushorts): 1168B = 16B-aligned, 2-way banks
#define KITER 18       // K = 576 = 528 quad | 1 bias-one | 32 y | 15 pad
// extended hidden layout (768 cols): 0..699 = net2 hidden, 700..749 = net1 hidden,
// 750 = bias channel (h==1.0 exactly), 751..767 = zero pad

typedef __attribute__((ext_vector_type(8))) short  short8x;
typedef __attribute__((ext_vector_type(4))) float  floatx4;

static __device__ __forceinline__ unsigned short f2bf(float f) {
    __hip_bfloat16 h = __float2bfloat16(f);   // RNE
    return __builtin_bit_cast(unsigned short, h);
}
static __device__ __forceinline__ float bf2f(unsigned short u) {
    unsigned int x = (unsigned int)u << 16;
    return __builtin_bit_cast(float, x);
}
// clampless tanh: exp2 overflow->+inf -> rcp(inf)=0 -> 1; underflow->0 -> -1.
// MUST stay bit-identical between prep (bias channel) and fused epilogue.
static __device__ __forceinline__ float tanh_fast(float x) {
    float e = __builtin_amdgcn_exp2f(x * 2.885390082f);   // e^(2x)
    return 1.f - 2.f * __builtin_amdgcn_rcpf(e + 1.f);
}

// ---------------- prep: extended pre-fragmented bf16 weight layouts ----------------
// W2aT: [k=0..17][panel p=0..47][lane 0..63][j 0..7]  (442368 ushorts)
//   B1[kk][c], kk = k*32+(lane>>4)*8+j, c = p*16+(lane&15):
//     c<700:   kk<528 -> W2a[kk][c]; kk==528 -> b2a[c]
//     c<750:   kk==528 -> b1a[c-700]; 529<=kk<561 -> W1a[kk-529][c-700]
//     c==750:  kk==528 -> 1.0
// W2bT: [wave w=0..15][ks=0..1][of=0..1][lane][j]     (32768 ushorts)
//   B2[kg][c], kg = w*48 + local k:
//     kg<700 -> W2b[kg][c]; kg<750 -> W1b[kg-700][c];
//     kg==750 -> (b1b[c]+b2b[c]) / tanh_fast(1.0)   (bias via tanh(1.0) channel)
__global__ void prep_kernel(const float* __restrict__ W2a, const float* __restrict__ b2a,
                            const float* __restrict__ W2b,
                            const float* __restrict__ W1a, const float* __restrict__ b1a,
                            const float* __restrict__ W1b, const float* __restrict__ b1b,
                            const float* __restrict__ b2b,
                            unsigned short* __restrict__ W2aT,
                            unsigned short* __restrict__ W2bT) {
    int idx = blockIdx.x * 256 + threadIdx.x;
    const int N1 = KITER * 48 * 512;   // 442368
    const int N2 = 16 * 4 * 512;       // 32768
    if (idx < N1) {
        int k   = idx / (48 * 512);
        int rem = idx - k * (48 * 512);
        int p   = rem >> 9;
        int q   = rem & 511;
        int ln  = q >> 3, j = q & 7;
        int kk  = k * 32 + ((ln >> 4) << 3) + j;
        int c   = (p << 4) + (ln & 15);
        float v = 0.f;
        if (c < H2) {
            if (kk < QF)       v = W2a[kk * H2 + c];
            else if (kk == QF) v = b2a[c];
        } else if (c < H2 + H1) {
            int cc = c - H2;
            if (kk == QF)                        v = b1a[cc];
            else if (kk > QF && kk < QF + 1 + D) v = W1a[(kk - QF - 1) * H1 + cc];
        } else if (c == H2 + H1) {
            if (kk == QF) v = 1.0f;
        }
        W2aT[idx] = f2bf(v);
    } else if (idx < N1 + N2) {
        int i2 = idx - N1;
        int q  = i2 & 511;
        int ln = q >> 3, j = q & 7;
        int w  = i2 >> 11;
        int ks = (i2 >> 10) & 1;
        int of = (i2 >> 9) & 1;
        int kl = (ks << 5) + ((ln >> 4) << 3) + j;   // local k 0..63
        int kg = w * 48 + kl;
        int c  = (of << 4) + (ln & 15);
        float v = 0.f;
        if (kl < 48) {
            if (kg < H2)            v = W2b[kg * D + c];
            else if (kg < H2 + H1)  v = W1b[(kg - H2) * D + c];
            else if (kg == H2 + H1) v = (b1b[c] + b2b[c]) / tanh_fast(1.0f);
        }
        W2bT[i2] = f2bf(v);
    }
}

// ---------------- fused main kernel ----------------
// r8 geometry + phase order (both load-bearing: r9/r10 showed phase overlap or
// deep-unroll chains blow the 64-reg budget -> 600 MB spills). net1 is GONE —
// folded into the extended GEMMs via K=576 and hidden cols 700..750.
__global__ __launch_bounds__(1024, 8)
__attribute__((amdgpu_waves_per_eu(8, 8)))
void fused_kernel(
    const float* __restrict__ y,
    const unsigned short* __restrict__ W2aT, const unsigned short* __restrict__ W2bT,
    float* __restrict__ out) {

    __shared__ unsigned short quadls[MROWS][QSTR]; // 37376 B; post-K reused as bf16 stage [16][1024]
    __shared__ float          yls[MROWS][36];      //  4608 B
    __shared__ unsigned short hst[16][16][68];     // 34816 B  => total 76800 B (2 blocks/CU)

    const int tid  = threadIdx.x;
    const int lane = tid & 63;
    const int w    = tid >> 6;                         // wave 0..15
    const int wu   = __builtin_amdgcn_readfirstlane(w);
    const int l15  = lane & 15;
    const int lg   = lane >> 4;                        // 0..3
    const int row0 = blockIdx.x * MROWS;

    // ---- Phase A: y tile (coalesced); zero hst K-pad cols 48..63 (wave-local) ----
    yls[tid >> 5][tid & 31] = y[row0 * D + tid];
    {
        int rr = lane >> 2, cc0 = 48 + (lane & 3) * 4;
        *reinterpret_cast<unsigned long long*>(&hst[w][rr][cc0]) = 0ULL;
    }
    __syncthreads();

    // ---- Phase B: A-matrix build: quad | 1.0 | y | pad (1 (row,i) task/thread) ----
    {
        int r = tid >> 5, i = tid & 31;
        int base = (i * (i + 1)) >> 1;
        float yi = yls[r][i];
        for (int j4 = 0; j4 <= i; j4 += 4) {
            floatx4 yv = *reinterpret_cast<const floatx4*>(&yls[r][j4]);
            #pragma unroll
            for (int jj = 0; jj < 4; ++jj) {
                int j = j4 + jj;
                if (j <= i) quadls[r][base + j] = f2bf(yi * yv[jj]);
            }
        }
        quadls[r][529 + i] = f2bf(yi);                         // y channels 529..560
        if (i == 0)  quadls[r][528] = (unsigned short)0x3F80;  // bias-one channel
        if (i < 15)  quadls[r][561 + i] = 0;                   // K-pad 561..575
    }
    __syncthreads();

    // ---- K-loop: wave w owns hidden cols [w*48, w*48+48), K = 576 ----
    floatx4 hacc00 = {0,0,0,0}, hacc01 = {0,0,0,0}, hacc02 = {0,0,0,0};
    floatx4 hacc10 = {0,0,0,0}, hacc11 = {0,0,0,0}, hacc12 = {0,0,0,0};
    {
        const unsigned short* bp = W2aT + wu * 3 * 512 + lane * 8;
        #pragma unroll 1
        for (int k = 0; k < KITER; ++k) {
            short8x a0 = *reinterpret_cast<const short8x*>(&quadls[l15][k * 32 + lg * 8]);
            short8x a1 = *reinterpret_cast<const short8x*>(&quadls[16 + l15][k * 32 + lg * 8]);
            short8x b0 = *reinterpret_cast<const short8x*>(bp);
            short8x b1 = *reinterpret_cast<const short8x*>(bp + 512);
            short8x b2 = *reinterpret_cast<const short8x*>(bp + 1024);
            hacc00 = __builtin_amdgcn_mfma_f32_16x16x32_bf16(a0, b0, hacc00, 0, 0, 0);
            hacc01 = __builtin_amdgcn_mfma_f32_16x16x32_bf16(a0, b1, hacc01, 0, 0, 0);
            hacc02 = __builtin_amdgcn_mfma_f32_16x16x32_bf16(a0, b2, hacc02, 0, 0, 0);
            hacc10 = __builtin_amdgcn_mfma_f32_16x16x32_bf16(a1, b0, hacc10, 0, 0, 0);
            hacc11 = __builtin_amdgcn_mfma_f32_16x16x32_bf16(a1, b1, hacc11, 0, 0, 0);
            hacc12 = __builtin_amdgcn_mfma_f32_16x16x32_bf16(a1, b2, hacc12, 0, 0, 0);
            bp += 48 * 512;
        }
    }
    __syncthreads();   // all quadls K-reads complete -> stage region is free

    // ---- epilogue: tanh -> hst -> GEMM2 (transient o2) -> packed bf16 stage ----
    // stage layout: flat f = row*32 + 2*l15 + of  holds col (of*16 + l15)
    unsigned short* stage = &quadls[0][0];
    {
        const unsigned short* wb = W2bT + wu * 4 * 512 + lane * 8;
        #pragma unroll
        for (int m = 0; m < 2; ++m) {
            const floatx4 h0 = m ? hacc10 : hacc00;
            const floatx4 h1 = m ? hacc11 : hacc01;
            const floatx4 h2 = m ? hacc12 : hacc02;
            #pragma unroll
            for (int r = 0; r < 4; ++r) {
                hst[w][lg * 4 + r][l15]      = f2bf(tanh_fast(h0[r]));
                hst[w][lg * 4 + r][16 + l15] = f2bf(tanh_fast(h1[r]));
                hst[w][lg * 4 + r][32 + l15] = f2bf(tanh_fast(h2[r]));
            }
            short8x aa0 = *reinterpret_cast<const short8x*>(&hst[w][l15][lg * 8]);
            short8x aa1 = *reinterpret_cast<const short8x*>(&hst[w][l15][32 + lg * 8]);
            floatx4 o20 = {0,0,0,0}, o21 = {0,0,0,0};
            {
                short8x bw00 = *reinterpret_cast<const short8x*>(wb);
                short8x bw01 = *reinterpret_cast<const short8x*>(wb + 512);
                o20 = __builtin_amdgcn_mfma_f32_16x16x32_bf16(aa0, bw00, o20, 0, 0, 0);
                o21 = __builtin_amdgcn_mfma_f32_16x16x32_bf16(aa0, bw01, o21, 0, 0, 0);
            }
            {
                short8x bw10 = *reinterpret_cast<const short8x*>(wb + 1024);
                short8x bw11 = *reinterpret_cast<const short8x*>(wb + 1536);
                o20 = __builtin_amdgcn_mfma_f32_16x16x32_bf16(aa1, bw10, o20, 0, 0, 0);
                o21 = __builtin_amdgcn_mfma_f32_16x16x32_bf16(aa1, bw11, o21, 0, 0, 0);
            }
            #pragma unroll
            for (int r = 0; r < 4; ++r) {
                int row = m * 16 + lg * 4 + r;
                unsigned int pk = ((unsigned int)f2bf(o21[r]) << 16) | (unsigned int)f2bf(o20[r]);
                *reinterpret_cast<unsigned int*>(&stage[wu * 1024 + row * 32 + l15 * 2]) = pk;
            }
        }
    }
    __syncthreads();   // all stage writes visible

    // ---- reduce 16 bf16 panels (biases already inside via col-750 channel) ----
    {
        int c  = tid & 31;
        int fr = (tid & ~31) + ((c & 15) << 1) + (c >> 4);   // packed-layout remap
        float s0 = 0.f, s1 = 0.f;
        #pragma unroll
        for (int p = 0; p < 16; p += 2) {
            s0 += bf2f(stage[p * 1024 + fr]);
            s1 += bf2f(stage[(p + 1) * 1024 + fr]);
        }
        out[row0 * D + tid] = s0 + s1;
    }
}

extern "C" void kernel_launch(void* const* d_in, const int* in_sizes, int n_in,
                              void* d_out, int out_size, void* d_ws, size_t ws_size,
                              hipStream_t stream) {
    const float* y   = (const float*)d_in[1];
    const float* W1a = (const float*)d_in[2];
    const float* b1a = (const float*)d_in[3];
    const float* W1b = (const float*)d_in[4];
    const float* b1b = (const float*)d_in[5];
    const float* W2a = (const float*)d_in[6];
    const float* b2a = (const float*)d_in[7];
    const float* W2b = (const float*)d_in[8];
    const float* b2b = (const float*)d_in[9];

    unsigned short* W2aT = (unsigned short*)d_ws;                      // 884736 B
    unsigned short* W2bT = (unsigned short*)((char*)d_ws + 884736);    //  65536 B

    const int prep_tasks = KITER * 48 * 512 + 16 * 4 * 512;            // 475136
    prep_kernel<<<(prep_tasks + 255) / 256, 256, 0, stream>>>(
        W2a, b2a, W2b, W1a, b1a, W1b, b1b, b2b, W2aT, W2bT);
    fused_kernel<<<B_TOT / MROWS, 1024, 0, stream>>>(y, W2aT, W2bT, (float*)d_out);
}